// Round 4
// baseline (614.307 us; speedup 1.0000x reference)
//
#include <hip/hip_runtime.h>
#include <hip/hip_bf16.h>

// WindowAttention fused kernel for MI355X (gfx950) — R2.
// Head-partitioned: wave h owns head h end-to-end (QKV -> attn -> PV) in a
// private 8KB LDS slice (same-wave DS ops are in-order -> no barriers).
// Only 2 barriers total (attnout exchange for proj). 32KB LDS, 4 blocks/CU.
// All bf16 packing via v_cvt_pk_bf16_f32 (__float22bfloat162_rn).
// Softmax in exp2 domain: log2e folded into Q-scale and comb table.

typedef short bf16x8 __attribute__((ext_vector_type(8)));
typedef float f32x4 __attribute__((ext_vector_type(4)));
#define MFMA __builtin_amdgcn_mfma_f32_16x16x32_bf16

#define NTOK 49
#define CDIM 128
#define NHEAD 4
#define LOG2E 1.4426950408889634f

__device__ __forceinline__ unsigned short f2bf(float f) {  // prep kernels only
    unsigned int u = __float_as_uint(f);
    u += 0x7fffu + ((u >> 16) & 1u);
    return (unsigned short)(u >> 16);
}
__device__ __forceinline__ unsigned pk2(float a, float b) {
    union { __hip_bfloat162 h; unsigned u; } t;
    t.h = __float22bfloat162_rn(make_float2(a, b));
    return t.u;
}
__device__ __forceinline__ float bflo(unsigned u) { return __uint_as_float(u << 16); }
__device__ __forceinline__ float bfhi(unsigned u) { return __uint_as_float(u & 0xffff0000u); }

union BF8 { bf16x8 v; unsigned u[4]; };

__global__ void prep_w(const float* __restrict__ qkv_w, const float* __restrict__ proj_w,
                       unsigned short* __restrict__ wq, unsigned short* __restrict__ wp) {
    int i = blockIdx.x * 256 + threadIdx.x;
    if (i < 384 * 128) wq[i] = f2bf(qkv_w[i]);   // [out_ch][in_ch] row-major
    if (i < 128 * 128) wp[i] = f2bf(proj_w[i]);
}

// comb[wm][h][q64][key64] bf16 = (rpb[rel[q][k]][h] + mask[wm][q][k]) * LOG2E
// pads: key>=49 -> -1e30, q>=49 -> 0
__global__ void prep_comb(const float* __restrict__ mask, const float* __restrict__ rpb,
                          const int* __restrict__ rel, unsigned short* __restrict__ comb, int nW) {
    int idx = blockIdx.x * 256 + threadIdx.x;
    int key = idx & 63;
    int q   = (idx >> 6) & 63;
    int h   = (idx >> 12) & 3;
    int wm  = idx >> 14;
    if (wm >= nW) return;
    float v;
    if (key >= NTOK)      v = -1e30f;
    else if (q >= NTOK)   v = 0.0f;
    else v = (rpb[rel[q * NTOK + key] * NHEAD + h] +
              mask[(size_t)wm * (NTOK * NTOK) + q * NTOK + key]) * LOG2E;
    comb[idx] = f2bf(v);
}

// LDS (32 KB): 4 per-head slices of 8 KB.
//  slice phase A: qk bf16[64 tok][64 ch] (Q ch 0-31, K ch 32-63), stride 128B, swz
//  slice phase B: vt bf16[32 ch][64 tok] @ +0 (4KB) | P ping-pong [16 q][64 key] @ +4096/+6144
//  after b1: attnout bf16[64 tok][128 ch] @ smem[0,16384) (aliases slices 0,1)
template <bool USE_COMB>
__global__ void __launch_bounds__(256, 4)
win_attn_kernel(const float* __restrict__ x,
                const float* __restrict__ qkv_b, const float* __restrict__ proj_b,
                const unsigned short* __restrict__ wq, const unsigned short* __restrict__ wp,
                const unsigned short* __restrict__ comb,
                const float* __restrict__ mask, const float* __restrict__ rpb,
                const int* __restrict__ rel,
                float* __restrict__ out, int nW) {
    __shared__ __align__(16) unsigned char smem[32768];

    const int tid = threadIdx.x;
    const int wid = tid >> 6;
    const int lane = tid & 63;
    const int l15 = lane & 15;
    const int lhi = lane >> 4;
    const int win = blockIdx.x;
    const int wm  = win % nW;
    const int h   = wid;
    unsigned char* slice = smem + h * 8192;
    const int swz = (l15 & 7) << 4;   // all our LDS rows satisfy row%16 == l15

    // ---------- x fragments from global (B operand: n=tok=l15, k=in_ch=8lhi+j) ----------
    const float* xw = x + (size_t)win * (NTOK * CDIM);
    bf16x8 xf[4][4];
#pragma unroll
    for (int tt = 0; tt < 4; ++tt) {
        const int tok = tt * 16 + l15;
        const bool valid = (tt < 3) || (l15 == 0);
#pragma unroll
        for (int ks = 0; ks < 4; ++ks) {
            float4 a = {0.f, 0.f, 0.f, 0.f}, b = {0.f, 0.f, 0.f, 0.f};
            if (valid) {
                const float* p = xw + tok * CDIM + ks * 32 + lhi * 8;
                a = reinterpret_cast<const float4*>(p)[0];
                b = reinterpret_cast<const float4*>(p)[1];
            }
            BF8 t;
            t.u[0] = pk2(a.x, a.y); t.u[1] = pk2(a.z, a.w);
            t.u[2] = pk2(b.x, b.y); t.u[3] = pk2(b.z, b.w);
            xf[tt][ks] = t.v;
        }
    }

    // ---------- phase 1a: Q,K for head h (swapped mfma -> 4 consecutive ch per lane) ----------
    const float qsc = 0.17677669529663687f * LOG2E;   // 1/sqrt(32) * log2(e)
#pragma unroll
    for (int cc = 0; cc < 4; ++cc) {
        const int cbase = (cc < 2) ? (h * 32 + cc * 16) : (128 + h * 32 + (cc - 2) * 16);
        bf16x8 wf[4];
#pragma unroll
        for (int ks = 0; ks < 4; ++ks)
            wf[ks] = *reinterpret_cast<const bf16x8*>(wq + (cbase + l15) * CDIM + ks * 32 + lhi * 8);
        const float4 b4 = *reinterpret_cast<const float4*>(qkv_b + cbase + lhi * 4);
        const float sc = (cc < 2) ? qsc : 1.0f;
#pragma unroll
        for (int tt = 0; tt < 4; ++tt) {
            f32x4 acc = {0.f, 0.f, 0.f, 0.f};
#pragma unroll
            for (int ks = 0; ks < 4; ++ks) acc = MFMA(wf[ks], xf[tt][ks], acc, 0, 0, 0);
            const int tok = tt * 16 + l15;
            uint2 u;
            u.x = pk2((acc[0] + b4.x) * sc, (acc[1] + b4.y) * sc);
            u.y = pk2((acc[2] + b4.z) * sc, (acc[3] + b4.w) * sc);
            *reinterpret_cast<uint2*>(&slice[tok * 128 + (((cc * 16 + lhi * 4) * 2) ^ swz)]) = u;
        }
    }

    // ---------- phase 1b: V for head h (normal mfma -> 4 consecutive toks per lane), keep in regs ----------
    uint2 vu[2][4];
#pragma unroll
    for (int cc = 0; cc < 2; ++cc) {
        const int cbase = 256 + h * 32 + cc * 16;
        bf16x8 wf[4];
#pragma unroll
        for (int ks = 0; ks < 4; ++ks)
            wf[ks] = *reinterpret_cast<const bf16x8*>(wq + (cbase + l15) * CDIM + ks * 32 + lhi * 8);
        const float bs = qkv_b[cbase + l15];
#pragma unroll
        for (int tt = 0; tt < 4; ++tt) {
            f32x4 acc = {0.f, 0.f, 0.f, 0.f};
#pragma unroll
            for (int ks = 0; ks < 4; ++ks) acc = MFMA(xf[tt][ks], wf[ks], acc, 0, 0, 0);
            vu[cc][tt].x = pk2(acc[0] + bs, acc[1] + bs);
            vu[cc][tt].y = pk2(acc[2] + bs, acc[3] + bs);
        }
    }

    // ---------- per-wave LDS: read qf/kf, then overwrite with vt (same-wave DS is in-order) ----------
    bf16x8 qf[4], kf[4];
#pragma unroll
    for (int t = 0; t < 4; ++t) {
        const int row = t * 16 + l15;
        qf[t] = *reinterpret_cast<const bf16x8*>(&slice[row * 128 + ((16 * lhi) ^ swz)]);
        kf[t] = *reinterpret_cast<const bf16x8*>(&slice[row * 128 + ((64 + 16 * lhi) ^ swz)]);
    }
#pragma unroll
    for (int cc = 0; cc < 2; ++cc) {
        const int vr = cc * 16 + l15;
#pragma unroll
        for (int tt = 0; tt < 4; ++tt)
            *reinterpret_cast<uint2*>(&slice[vr * 128 + (((tt * 16 + lhi * 4) * 2) ^ swz)]) = vu[cc][tt];
    }
    bf16x8 vf[2][2];
#pragma unroll
    for (int dt = 0; dt < 2; ++dt)
#pragma unroll
        for (int ks = 0; ks < 2; ++ks)
            vf[dt][ks] = *reinterpret_cast<const bf16x8*>(
                &slice[(dt * 16 + l15) * 128 + (((ks * 32 + lhi * 8) * 2) ^ swz)]);

    // ---------- phase 2: attention for head h (no barriers; P ping-pong in private slice) ----------
    const unsigned short* cwh = comb + ((size_t)(wm * NHEAD + h) << 12);
    uint2 cb[4];
    if (USE_COMB) {
#pragma unroll
        for (int kt = 0; kt < 4; ++kt)
            cb[kt] = *reinterpret_cast<const uint2*>(cwh + l15 * 64 + kt * 16 + lhi * 4);
    }
    float inv[4];
    uint2 ou[4][2];
#pragma unroll
    for (int qt = 0; qt < 4; ++qt) {
        uint2 cbn[4];
        if (USE_COMB && qt < 3) {
#pragma unroll
            for (int kt = 0; kt < 4; ++kt)
                cbn[kt] = *reinterpret_cast<const uint2*>(cwh + ((qt + 1) * 16 + l15) * 64 + kt * 16 + lhi * 4);
        }
        f32x4 sv[4];
#pragma unroll
        for (int kt = 0; kt < 4; ++kt) {
            f32x4 c;
            if (USE_COMB) {
                c[0] = bflo(cb[kt].x); c[1] = bfhi(cb[kt].x);
                c[2] = bflo(cb[kt].y); c[3] = bfhi(cb[kt].y);
            } else {
                const int q = qt * 16 + l15;
#pragma unroll
                for (int r = 0; r < 4; ++r) {
                    const int key = kt * 16 + lhi * 4 + r;
                    float v;
                    if (key >= NTOK)    v = -1e30f;
                    else if (q >= NTOK) v = 0.0f;
                    else v = (rpb[rel[q * NTOK + key] * NHEAD + h] +
                              mask[(size_t)wm * (NTOK * NTOK) + q * NTOK + key]) * LOG2E;
                    c[r] = v;
                }
            }
            sv[kt] = MFMA(kf[kt], qf[qt], c, 0, 0, 0);   // S[key=16kt+4lhi+r][q=16qt+l15] (log2 domain)
        }
        // softmax over keys (16 in-lane + cross-lhi via shfl_xor 16,32)
        float m = sv[0][0];
#pragma unroll
        for (int kt = 0; kt < 4; ++kt)
#pragma unroll
            for (int r = 0; r < 4; ++r) m = fmaxf(m, sv[kt][r]);
        m = fmaxf(m, __shfl_xor(m, 16));
        m = fmaxf(m, __shfl_xor(m, 32));
        float sum = 0.f;
#pragma unroll
        for (int kt = 0; kt < 4; ++kt)
#pragma unroll
            for (int r = 0; r < 4; ++r) {
                const float p = exp2f(sv[kt][r] - m);
                sv[kt][r] = p;
                sum += p;
            }
        sum += __shfl_xor(sum, 16);
        sum += __shfl_xor(sum, 32);
        inv[qt] = __builtin_amdgcn_rcpf(sum);
        // write unnormalized P to ping-pong buffer [16 q][64 key]
        unsigned char* Pb = slice + 4096 + (qt & 1) * 2048;
#pragma unroll
        for (int kt = 0; kt < 4; ++kt) {
            uint2 u;
            u.x = pk2(sv[kt][0], sv[kt][1]);
            u.y = pk2(sv[kt][2], sv[kt][3]);
            *reinterpret_cast<uint2*>(&Pb[l15 * 128 + (((kt * 16 + lhi * 4) * 2) ^ swz)]) = u;
        }
        bf16x8 pf0 = *reinterpret_cast<const bf16x8*>(&Pb[l15 * 128 + ((lhi * 16) ^ swz)]);
        bf16x8 pf1 = *reinterpret_cast<const bf16x8*>(&Pb[l15 * 128 + ((64 + lhi * 16) ^ swz)]);
        // PV: O[d=16dt+4lhi+r][q=16qt+l15]
        f32x4 o0 = {0.f, 0.f, 0.f, 0.f}, o1 = {0.f, 0.f, 0.f, 0.f};
        o0 = MFMA(vf[0][0], pf0, o0, 0, 0, 0);
        o0 = MFMA(vf[0][1], pf1, o0, 0, 0, 0);
        o1 = MFMA(vf[1][0], pf0, o1, 0, 0, 0);
        o1 = MFMA(vf[1][1], pf1, o1, 0, 0, 0);
        const float iv = inv[qt];
        ou[qt][0].x = pk2(o0[0] * iv, o0[1] * iv);
        ou[qt][0].y = pk2(o0[2] * iv, o0[3] * iv);
        ou[qt][1].x = pk2(o1[0] * iv, o1[1] * iv);
        ou[qt][1].y = pk2(o1[2] * iv, o1[3] * iv);
        if (USE_COMB && qt < 3) {
#pragma unroll
            for (int kt = 0; kt < 4; ++kt) cb[kt] = cbn[kt];
        }
    }

    // ---------- prefetch proj weights/bias (independent of LDS) ----------
    bf16x8 wpf[2][4];
    float4 pb4[2];
#pragma unroll
    for (int ct = 0; ct < 2; ++ct) {
        const int ocb = wid * 32 + ct * 16;
#pragma unroll
        for (int ks = 0; ks < 4; ++ks)
            wpf[ct][ks] = *reinterpret_cast<const bf16x8*>(wp + (ocb + l15) * CDIM + ks * 32 + lhi * 8);
        pb4[ct] = *reinterpret_cast<const float4*>(proj_b + ocb + lhi * 4);
    }

    __syncthreads();  // b1: all private-slice reads done -> attnout may alias slices 0,1

    // attnout[64 tok][128 ch] bf16 @ smem[0,16384), stride 256B, swz
#pragma unroll
    for (int qt = 0; qt < 4; ++qt) {
        const int row = qt * 16 + l15;
#pragma unroll
        for (int dt = 0; dt < 2; ++dt)
            *reinterpret_cast<uint2*>(
                &smem[row * 256 + (((h * 32 + dt * 16 + lhi * 4) * 2) ^ swz)]) = ou[qt][dt];
    }
    __syncthreads();  // b2: attnout ready

    // ---------- phase 3: proj (swapped) -> float4 stores ----------
    bf16x8 aof[4][4];
#pragma unroll
    for (int tt = 0; tt < 4; ++tt)
#pragma unroll
        for (int ks = 0; ks < 4; ++ks) {
            const int row = tt * 16 + l15;
            aof[tt][ks] = *reinterpret_cast<const bf16x8*>(
                &smem[row * 256 + (((ks * 32 + lhi * 8) * 2) ^ swz)]);
        }
#pragma unroll
    for (int ct = 0; ct < 2; ++ct) {
        const int ocb = wid * 32 + ct * 16;
#pragma unroll
        for (int tt = 0; tt < 4; ++tt) {
            f32x4 c = {0.f, 0.f, 0.f, 0.f};
#pragma unroll
            for (int ks = 0; ks < 4; ++ks) c = MFMA(wpf[ct][ks], aof[tt][ks], c, 0, 0, 0);
            const int tok = tt * 16 + l15;
            if (tok < NTOK) {
                float4 r;
                r.x = c[0] + pb4[ct].x;
                r.y = c[1] + pb4[ct].y;
                r.z = c[2] + pb4[ct].z;
                r.w = c[3] + pb4[ct].w;
                *reinterpret_cast<float4*>(out + (size_t)win * (NTOK * CDIM) + tok * CDIM + ocb + lhi * 4) = r;
            }
        }
    }
}

extern "C" void kernel_launch(void* const* d_in, const int* in_sizes, int n_in,
                              void* d_out, int out_size, void* d_ws, size_t ws_size,
                              hipStream_t stream) {
    const float* x      = (const float*)d_in[0];
    const float* mask   = (const float*)d_in[1];
    const float* qkv_w  = (const float*)d_in[2];
    const float* qkv_b  = (const float*)d_in[3];
    const float* proj_w = (const float*)d_in[4];
    const float* proj_b = (const float*)d_in[5];
    const float* rpb    = (const float*)d_in[6];
    const int*   rel    = (const int*)d_in[7];

    const int Bw = in_sizes[0] / (NTOK * CDIM);   // 16384
    const int nW = in_sizes[1] / (NTOK * NTOK);   // 1024

    unsigned short* wq   = (unsigned short*)d_ws;            // 384*128 bf16
    unsigned short* wp   = wq + 384 * 128;                   // 128*128 bf16
    unsigned short* comb = wp + 128 * 128;                   // nW*4*64*64 bf16
    const size_t need = (size_t)(384 * 128 + 128 * 128) * 2 + (size_t)nW * NHEAD * 4096 * 2;

    prep_w<<<dim3(192), dim3(256), 0, stream>>>(qkv_w, proj_w, wq, wp);
    if (ws_size >= need) {
        const int nComb = nW * NHEAD * 4096;
        prep_comb<<<dim3((nComb + 255) / 256), dim3(256), 0, stream>>>(mask, rpb, rel, comb, nW);
        win_attn_kernel<true><<<dim3(Bw), dim3(256), 0, stream>>>(
            x, qkv_b, proj_b, wq, wp, comb, mask, rpb, rel, (float*)d_out, nW);
    } else {
        win_attn_kernel<false><<<dim3(Bw), dim3(256), 0, stream>>>(
            x, qkv_b, proj_b, wq, wp, nullptr, mask, rpb, rel, (float*)d_out, nW);
    }
}

// Round 5
// 604.641 us; speedup vs baseline: 1.0160x; 1.0160x over previous
//
#include <hip/hip_runtime.h>
#include <hip/hip_bf16.h>

// WindowAttention fused kernel for MI355X (gfx950) — R4.
// One block = one window (N=49 pad 64, C=128, H=4, hd=32), wave h = head h.
// x staged ONCE in LDS bf16 (cooperative) -> all GEMM A/B fragments via ds_read_b128.
// Biases ride the MFMA C operand; Q scale+log2e folded into weights at prep.
// Per-wave private 6KB LDS slice, same-wave DS in-order -> 3 barriers total.

typedef short bf16x8 __attribute__((ext_vector_type(8)));
typedef float f32x4 __attribute__((ext_vector_type(4)));
#define MFMA __builtin_amdgcn_mfma_f32_16x16x32_bf16

#define NTOK 49
#define CDIM 128
#define NHEAD 4
#define LOG2E 1.4426950408889634f
#define QSC (0.17677669529663687f * LOG2E)   // 1/sqrt(32) * log2(e)

__device__ __forceinline__ unsigned short f2bf(float f) {  // prep kernels only
    unsigned int u = __float_as_uint(f);
    u += 0x7fffu + ((u >> 16) & 1u);
    return (unsigned short)(u >> 16);
}
__device__ __forceinline__ unsigned pk2(float a, float b) {
    union { __hip_bfloat162 h; unsigned u; } t;
    t.h = __float22bfloat162_rn(make_float2(a, b));
    return t.u;
}
__device__ __forceinline__ float bflo(unsigned u) { return __uint_as_float(u << 16); }
__device__ __forceinline__ float bfhi(unsigned u) { return __uint_as_float(u & 0xffff0000u); }

__global__ void prep_w(const float* __restrict__ qkv_w, const float* __restrict__ proj_w,
                       const float* __restrict__ qkv_b,
                       unsigned short* __restrict__ wq, unsigned short* __restrict__ wp,
                       float* __restrict__ qb2) {
    int i = blockIdx.x * 256 + threadIdx.x;
    if (i < 384 * 128) {
        float v = qkv_w[i];
        if (i < 128 * 128) v *= QSC;          // fold attention scale+log2e into Q rows
        wq[i] = f2bf(v);
    }
    if (i < 128 * 128) wp[i] = f2bf(proj_w[i]);
    if (i < 384) {
        float b = qkv_b[i];
        if (i < 128) b *= QSC;
        qb2[i] = b;
    }
}

// comb[wm][h][q64][key64] bf16 = (rpb[rel[q][k]][h] + mask[wm][q][k]) * LOG2E
__global__ void prep_comb(const float* __restrict__ mask, const float* __restrict__ rpb,
                          const int* __restrict__ rel, unsigned short* __restrict__ comb, int nW) {
    int idx = blockIdx.x * 256 + threadIdx.x;
    int key = idx & 63;
    int q   = (idx >> 6) & 63;
    int h   = (idx >> 12) & 3;
    int wm  = idx >> 14;
    if (wm >= nW) return;
    float v;
    if (key >= NTOK)      v = -1e30f;
    else if (q >= NTOK)   v = 0.0f;
    else v = (rpb[rel[q * NTOK + key] * NHEAD + h] +
              mask[(size_t)wm * (NTOK * NTOK) + q * NTOK + key]) * LOG2E;
    comb[idx] = f2bf(v);
}

// LDS 40KB -> 4 blocks/CU:
//  [0,16384):  x bf16 [64 tok][128 ch] (256B rows, xor (row&7)<<4)  -> later attnout (same fmt)
//  slice(w) = 16384 + w*6144, 6KB/wave:
//    [0,5120):   Q then K then vt (sequential same-wave reuse)
//                Q/K: [64 tok][32ch=64B] stride 80 (bank-friendly, no xor)
//                vt:  [32 ch][64tok=128B] stride 128, xor (ch&3)<<4
//    [4096,6144): P [16 q][64key=128B] stride 128, xor (q&3)<<4 (Q/K dead by then)
template <bool USE_COMB>
__global__ void __launch_bounds__(256, 4)
win_attn_kernel(const float* __restrict__ x, const float* __restrict__ qb2,
                const float* __restrict__ proj_b,
                const unsigned short* __restrict__ wq, const unsigned short* __restrict__ wp,
                const unsigned short* __restrict__ comb,
                const float* __restrict__ mask, const float* __restrict__ rpb,
                const int* __restrict__ rel,
                float* __restrict__ out, int nW) {
    __shared__ __align__(16) unsigned char smem[40960];

    const int tid = threadIdx.x;
    const int wid = tid >> 6;
    const int lane = tid & 63;
    const int l15 = lane & 15;
    const int lhi = lane >> 4;
    const int win = blockIdx.x;
    const int wm  = win % nW;
    const int h   = wid;
    unsigned char* sl = smem + 16384 + h * 6144;

#define LDX(row, colb) (*reinterpret_cast<const bf16x8*>( \
        &smem[(row) * 256 + ((colb) ^ (((row) & 7) << 4))]))

    // ---------- early comb prefetch (qt=0): latency hides under QKV ----------
    const unsigned short* cwh = USE_COMB ? comb + ((size_t)(wm * NHEAD + h) << 12) : nullptr;
    uint2 cb[4];
    if (USE_COMB) {
#pragma unroll
        for (int kt = 0; kt < 4; ++kt)
            cb[kt] = *reinterpret_cast<const uint2*>(cwh + l15 * 64 + kt * 16 + lhi * 4);
    }

    // ---------- stage x -> LDS bf16, once per block ----------
    const float* xw = x + (size_t)win * (NTOK * CDIM);
#pragma unroll
    for (int i = 0; i < 4; ++i) {
        const int c = tid + i * 256;          // 0..1023
        const int row = c >> 4, col8 = c & 15;
        float4 a = {0.f, 0.f, 0.f, 0.f}, b = {0.f, 0.f, 0.f, 0.f};
        if (row < NTOK) {
            const float4* p = reinterpret_cast<const float4*>(xw + row * CDIM + col8 * 8);
            a = p[0]; b = p[1];
        }
        uint4 u;
        u.x = pk2(a.x, a.y); u.y = pk2(a.z, a.w);
        u.z = pk2(b.x, b.y); u.w = pk2(b.z, b.w);
        *reinterpret_cast<uint4*>(&smem[row * 256 + ((col8 * 16) ^ ((row & 7) << 4))]) = u;
    }
    __syncthreads();  // b0: x staged

    // ---------- Q (ch 32h..32h+31), bias in C, scale pre-folded ----------
    bf16x8 qf[4], kf[4];
#pragma unroll
    for (int cc = 0; cc < 2; ++cc) {
        const int ch0 = h * 32 + cc * 16;
        bf16x8 wf[4];
#pragma unroll
        for (int ks = 0; ks < 4; ++ks)
            wf[ks] = *reinterpret_cast<const bf16x8*>(wq + (ch0 + l15) * CDIM + ks * 32 + lhi * 8);
        const float4 b4 = *reinterpret_cast<const float4*>(qb2 + ch0 + lhi * 4);
#pragma unroll
        for (int tt = 0; tt < 4; ++tt) {
            const int row = tt * 16 + l15;
            f32x4 acc = {b4.x, b4.y, b4.z, b4.w};
#pragma unroll
            for (int ks = 0; ks < 4; ++ks)
                acc = MFMA(wf[ks], LDX(row, ks * 64 + lhi * 16), acc, 0, 0, 0);
            uint2 u; u.x = pk2(acc[0], acc[1]); u.y = pk2(acc[2], acc[3]);
            *reinterpret_cast<uint2*>(&sl[row * 80 + cc * 32 + lhi * 8]) = u;
        }
    }
#pragma unroll
    for (int t = 0; t < 4; ++t)
        qf[t] = *reinterpret_cast<const bf16x8*>(&sl[(t * 16 + l15) * 80 + lhi * 16]);

    // ---------- K (ch 128+32h..), overwrites Q region (same-wave in-order) ----------
#pragma unroll
    for (int cc = 0; cc < 2; ++cc) {
        const int ch0 = 128 + h * 32 + cc * 16;
        bf16x8 wf[4];
#pragma unroll
        for (int ks = 0; ks < 4; ++ks)
            wf[ks] = *reinterpret_cast<const bf16x8*>(wq + (ch0 + l15) * CDIM + ks * 32 + lhi * 8);
        const float4 b4 = *reinterpret_cast<const float4*>(qb2 + ch0 + lhi * 4);
#pragma unroll
        for (int tt = 0; tt < 4; ++tt) {
            const int row = tt * 16 + l15;
            f32x4 acc = {b4.x, b4.y, b4.z, b4.w};
#pragma unroll
            for (int ks = 0; ks < 4; ++ks)
                acc = MFMA(wf[ks], LDX(row, ks * 64 + lhi * 16), acc, 0, 0, 0);
            uint2 u; u.x = pk2(acc[0], acc[1]); u.y = pk2(acc[2], acc[3]);
            *reinterpret_cast<uint2*>(&sl[row * 80 + cc * 32 + lhi * 8]) = u;
        }
    }
#pragma unroll
    for (int t = 0; t < 4; ++t)
        kf[t] = *reinterpret_cast<const bf16x8*>(&sl[(t * 16 + l15) * 80 + lhi * 16]);

    // ---------- V (ch 256+32h..), normal mfma -> vt[ch][tok], overwrites Q/K region ----------
#pragma unroll
    for (int cc = 0; cc < 2; ++cc) {
        const int ch0 = 256 + h * 32 + cc * 16;
        bf16x8 wf[4];
#pragma unroll
        for (int ks = 0; ks < 4; ++ks)
            wf[ks] = *reinterpret_cast<const bf16x8*>(wq + (ch0 + l15) * CDIM + ks * 32 + lhi * 8);
        const float bs = qb2[ch0 + l15];
        const int ch = cc * 16 + l15;         // head-relative channel 0..31
#pragma unroll
        for (int tt = 0; tt < 4; ++tt) {
            const int row = tt * 16 + l15;
            f32x4 acc = {bs, bs, bs, bs};
#pragma unroll
            for (int ks = 0; ks < 4; ++ks)
                acc = MFMA(LDX(row, ks * 64 + lhi * 16), wf[ks], acc, 0, 0, 0);
            uint2 u; u.x = pk2(acc[0], acc[1]); u.y = pk2(acc[2], acc[3]);
            *reinterpret_cast<uint2*>(&sl[ch * 128 + ((tt * 32 + lhi * 8) ^ ((ch & 3) << 4))]) = u;
        }
    }
    bf16x8 vf[2][2];
#pragma unroll
    for (int dt = 0; dt < 2; ++dt)
#pragma unroll
        for (int ks = 0; ks < 2; ++ks)
            vf[dt][ks] = *reinterpret_cast<const bf16x8*>(
                &sl[(dt * 16 + l15) * 128 + ((ks * 64 + lhi * 16) ^ ((l15 & 3) << 4))]);

    // ---------- attention (private slice, no barriers) ----------
    unsigned char* Pb = sl + 4096;
    uint2 ou[4][2];
#pragma unroll
    for (int qt = 0; qt < 4; ++qt) {
        uint2 cbn[4];
        if (USE_COMB && qt < 3) {
#pragma unroll
            for (int kt = 0; kt < 4; ++kt)
                cbn[kt] = *reinterpret_cast<const uint2*>(
                    cwh + ((qt + 1) * 16 + l15) * 64 + kt * 16 + lhi * 4);
        }
        f32x4 sv[4];
#pragma unroll
        for (int kt = 0; kt < 4; ++kt) {
            f32x4 c;
            if (USE_COMB) {
                c[0] = bflo(cb[kt].x); c[1] = bfhi(cb[kt].x);
                c[2] = bflo(cb[kt].y); c[3] = bfhi(cb[kt].y);
            } else {
                const int q = qt * 16 + l15;
#pragma unroll
                for (int r = 0; r < 4; ++r) {
                    const int key = kt * 16 + lhi * 4 + r;
                    float v;
                    if (key >= NTOK)    v = -1e30f;
                    else if (q >= NTOK) v = 0.0f;
                    else v = (rpb[rel[q * NTOK + key] * NHEAD + h] +
                              mask[(size_t)wm * (NTOK * NTOK) + q * NTOK + key]) * LOG2E;
                    c[r] = v;
                }
            }
            sv[kt] = MFMA(kf[kt], qf[qt], c, 0, 0, 0);  // S[key=16kt+4lhi+r][q=16qt+l15], log2-domain
        }
        // max tree (max3-fusable)
        float a0 = fmaxf(fmaxf(sv[0][0], sv[0][1]), fmaxf(sv[0][2], sv[0][3]));
        float a1 = fmaxf(fmaxf(sv[1][0], sv[1][1]), fmaxf(sv[1][2], sv[1][3]));
        float a2 = fmaxf(fmaxf(sv[2][0], sv[2][1]), fmaxf(sv[2][2], sv[2][3]));
        float a3 = fmaxf(fmaxf(sv[3][0], sv[3][1]), fmaxf(sv[3][2], sv[3][3]));
        float m = fmaxf(fmaxf(a0, a1), fmaxf(a2, a3));
        m = fmaxf(m, __shfl_xor(m, 16));
        m = fmaxf(m, __shfl_xor(m, 32));
        float s0 = 0.f, s1 = 0.f, s2 = 0.f, s3 = 0.f;
#pragma unroll
        for (int kt = 0; kt < 4; ++kt) {
            sv[kt][0] = exp2f(sv[kt][0] - m);
            sv[kt][1] = exp2f(sv[kt][1] - m);
            sv[kt][2] = exp2f(sv[kt][2] - m);
            sv[kt][3] = exp2f(sv[kt][3] - m);
        }
        s0 = (sv[0][0] + sv[0][1]) + (sv[0][2] + sv[0][3]);
        s1 = (sv[1][0] + sv[1][1]) + (sv[1][2] + sv[1][3]);
        s2 = (sv[2][0] + sv[2][1]) + (sv[2][2] + sv[2][3]);
        s3 = (sv[3][0] + sv[3][1]) + (sv[3][2] + sv[3][3]);
        float sum = (s0 + s1) + (s2 + s3);
        sum += __shfl_xor(sum, 16);
        sum += __shfl_xor(sum, 32);
        const float iv = __builtin_amdgcn_rcpf(sum);

        // P write (single buffer; same-wave in-order) then fragment read
#pragma unroll
        for (int kt = 0; kt < 4; ++kt) {
            uint2 u; u.x = pk2(sv[kt][0], sv[kt][1]); u.y = pk2(sv[kt][2], sv[kt][3]);
            *reinterpret_cast<uint2*>(
                &Pb[l15 * 128 + ((kt * 32 + lhi * 8) ^ ((l15 & 3) << 4))]) = u;
        }
        bf16x8 pf0 = *reinterpret_cast<const bf16x8*>(&Pb[l15 * 128 + ((lhi * 16) ^ ((l15 & 3) << 4))]);
        bf16x8 pf1 = *reinterpret_cast<const bf16x8*>(&Pb[l15 * 128 + ((64 + lhi * 16) ^ ((l15 & 3) << 4))]);
        f32x4 o0 = {0.f, 0.f, 0.f, 0.f}, o1 = {0.f, 0.f, 0.f, 0.f};
        o0 = MFMA(vf[0][0], pf0, o0, 0, 0, 0);
        o0 = MFMA(vf[0][1], pf1, o0, 0, 0, 0);
        o1 = MFMA(vf[1][0], pf0, o1, 0, 0, 0);
        o1 = MFMA(vf[1][1], pf1, o1, 0, 0, 0);
        ou[qt][0].x = pk2(o0[0] * iv, o0[1] * iv);
        ou[qt][0].y = pk2(o0[2] * iv, o0[3] * iv);
        ou[qt][1].x = pk2(o1[0] * iv, o1[1] * iv);
        ou[qt][1].y = pk2(o1[2] * iv, o1[3] * iv);
        if (USE_COMB && qt < 3) {
#pragma unroll
            for (int kt = 0; kt < 4; ++kt) cb[kt] = cbn[kt];
        }
    }

    // ---------- proj weight prefetch (hides under barriers) ----------
    bf16x8 wpf[2][4];
    float4 pb4[2];
#pragma unroll
    for (int ct = 0; ct < 2; ++ct) {
        const int ocb = wid * 32 + ct * 16;
#pragma unroll
        for (int ks = 0; ks < 4; ++ks)
            wpf[ct][ks] = *reinterpret_cast<const bf16x8*>(wp + (ocb + l15) * CDIM + ks * 32 + lhi * 8);
        pb4[ct] = *reinterpret_cast<const float4*>(proj_b + ocb + lhi * 4);
    }

    __syncthreads();  // b1: all waves done reading x region -> attnout may overwrite it

    // attnout [64 tok][128 ch] bf16 @ smem[0,16384), same fmt as x
#pragma unroll
    for (int qt = 0; qt < 4; ++qt) {
        const int row = qt * 16 + l15;
#pragma unroll
        for (int dt = 0; dt < 2; ++dt)
            *reinterpret_cast<uint2*>(
                &smem[row * 256 + ((h * 64 + dt * 32 + lhi * 8) ^ ((row & 7) << 4))]) = ou[qt][dt];
    }
    __syncthreads();  // b2: attnout ready

    // ---------- proj: bias in C, float4 stores ----------
    float* ow = out + (size_t)win * (NTOK * CDIM);
#pragma unroll
    for (int tt = 0; tt < 4; ++tt) {
        const int row = tt * 16 + l15;
        bf16x8 a4[4];
#pragma unroll
        for (int ks = 0; ks < 4; ++ks) a4[ks] = LDX(row, ks * 64 + lhi * 16);
#pragma unroll
        for (int ct = 0; ct < 2; ++ct) {
            f32x4 c = {pb4[ct].x, pb4[ct].y, pb4[ct].z, pb4[ct].w};
#pragma unroll
            for (int ks = 0; ks < 4; ++ks) c = MFMA(wpf[ct][ks], a4[ks], c, 0, 0, 0);
            if (row < NTOK) {
                float4 r; r.x = c[0]; r.y = c[1]; r.z = c[2]; r.w = c[3];
                *reinterpret_cast<float4*>(ow + row * CDIM + wid * 32 + ct * 16 + lhi * 4) = r;
            }
        }
    }
#undef LDX
}

extern "C" void kernel_launch(void* const* d_in, const int* in_sizes, int n_in,
                              void* d_out, int out_size, void* d_ws, size_t ws_size,
                              hipStream_t stream) {
    const float* x      = (const float*)d_in[0];
    const float* mask   = (const float*)d_in[1];
    const float* qkv_w  = (const float*)d_in[2];
    const float* qkv_b  = (const float*)d_in[3];
    const float* proj_w = (const float*)d_in[4];
    const float* proj_b = (const float*)d_in[5];
    const float* rpb    = (const float*)d_in[6];
    const int*   rel    = (const int*)d_in[7];

    const int Bw = in_sizes[0] / (NTOK * CDIM);   // 16384
    const int nW = in_sizes[1] / (NTOK * NTOK);   // 1024

    unsigned short* wq   = (unsigned short*)d_ws;                      // 384*128 bf16
    unsigned short* wp   = wq + 384 * 128;                             // 128*128 bf16
    float*          qb2  = (float*)(wp + 128 * 128);                   // 384 f32
    unsigned short* comb = (unsigned short*)(qb2 + 384);               // nW*4*4096 bf16
    const size_t need = (size_t)(384 * 128 + 128 * 128) * 2 + 384 * 4 +
                        (size_t)nW * NHEAD * 4096 * 2;

    prep_w<<<dim3(192), dim3(256), 0, stream>>>(qkv_w, proj_w, qkv_b, wq, wp, qb2);
    if (ws_size >= need) {
        const int nComb = nW * NHEAD * 4096;
        prep_comb<<<dim3((nComb + 255) / 256), dim3(256), 0, stream>>>(mask, rpb, rel, comb, nW);
        win_attn_kernel<true><<<dim3(Bw), dim3(256), 0, stream>>>(
            x, qb2, proj_b, wq, wp, comb, mask, rpb, rel, (float*)d_out, nW);
    } else {
        win_attn_kernel<false><<<dim3(Bw), dim3(256), 0, stream>>>(
            x, qb2, proj_b, wq, wp, nullptr, mask, rpb, rel, (float*)d_out, nW);
    }
}

// Round 6
// 486.785 us; speedup vs baseline: 1.2620x; 1.2421x over previous
//
#include <hip/hip_runtime.h>
#include <hip/hip_bf16.h>

// WindowAttention fused kernel for MI355X (gfx950) — R5.
// R4 + spill elimination: peak register demand cut below the 128/wave cap
// (attnout written directly per-qt after early b1; proj weights loaded after
// the attention loop), __launch_bounds__(256,3) as spill safety valve.

typedef short bf16x8 __attribute__((ext_vector_type(8)));
typedef float f32x4 __attribute__((ext_vector_type(4)));
#define MFMA __builtin_amdgcn_mfma_f32_16x16x32_bf16

#define NTOK 49
#define CDIM 128
#define NHEAD 4
#define LOG2E 1.4426950408889634f
#define QSC (0.17677669529663687f * LOG2E)   // 1/sqrt(32) * log2(e)

__device__ __forceinline__ unsigned short f2bf(float f) {  // prep kernels only
    unsigned int u = __float_as_uint(f);
    u += 0x7fffu + ((u >> 16) & 1u);
    return (unsigned short)(u >> 16);
}
__device__ __forceinline__ unsigned pk2(float a, float b) {
    union { __hip_bfloat162 h; unsigned u; } t;
    t.h = __float22bfloat162_rn(make_float2(a, b));
    return t.u;
}
__device__ __forceinline__ float bflo(unsigned u) { return __uint_as_float(u << 16); }
__device__ __forceinline__ float bfhi(unsigned u) { return __uint_as_float(u & 0xffff0000u); }

__global__ void prep_w(const float* __restrict__ qkv_w, const float* __restrict__ proj_w,
                       const float* __restrict__ qkv_b,
                       unsigned short* __restrict__ wq, unsigned short* __restrict__ wp,
                       float* __restrict__ qb2) {
    int i = blockIdx.x * 256 + threadIdx.x;
    if (i < 384 * 128) {
        float v = qkv_w[i];
        if (i < 128 * 128) v *= QSC;          // fold attention scale+log2e into Q rows
        wq[i] = f2bf(v);
    }
    if (i < 128 * 128) wp[i] = f2bf(proj_w[i]);
    if (i < 384) {
        float b = qkv_b[i];
        if (i < 128) b *= QSC;
        qb2[i] = b;
    }
}

// comb[wm][h][q64][key64] bf16 = (rpb[rel[q][k]][h] + mask[wm][q][k]) * LOG2E
__global__ void prep_comb(const float* __restrict__ mask, const float* __restrict__ rpb,
                          const int* __restrict__ rel, unsigned short* __restrict__ comb, int nW) {
    int idx = blockIdx.x * 256 + threadIdx.x;
    int key = idx & 63;
    int q   = (idx >> 6) & 63;
    int h   = (idx >> 12) & 3;
    int wm  = idx >> 14;
    if (wm >= nW) return;
    float v;
    if (key >= NTOK)      v = -1e30f;
    else if (q >= NTOK)   v = 0.0f;
    else v = (rpb[rel[q * NTOK + key] * NHEAD + h] +
              mask[(size_t)wm * (NTOK * NTOK) + q * NTOK + key]) * LOG2E;
    comb[idx] = f2bf(v);
}

// LDS 40KB -> 4 blocks/CU:
//  [0,16384):  x bf16 [64 tok][128 ch] (256B rows, xor (row&7)<<4)
//              -> after b1: attnout (same fmt), written per-qt during attention
//  slice(w) = 16384 + w*6144, 6KB/wave:
//    [0,5120):   Q then K then vt (sequential same-wave reuse)
//                Q/K: [64 tok][32ch=64B] stride 80 (bank-friendly, no xor)
//                vt:  [32 ch][64tok=128B] stride 128, xor (ch&3)<<4
//    [4096,6144): P [16 q][64key=128B] stride 128, xor (q&3)<<4 (Q/K dead by then)
template <bool USE_COMB>
__global__ void __launch_bounds__(256, 3)
win_attn_kernel(const float* __restrict__ x, const float* __restrict__ qb2,
                const float* __restrict__ proj_b,
                const unsigned short* __restrict__ wq, const unsigned short* __restrict__ wp,
                const unsigned short* __restrict__ comb,
                const float* __restrict__ mask, const float* __restrict__ rpb,
                const int* __restrict__ rel,
                float* __restrict__ out, int nW) {
    __shared__ __align__(16) unsigned char smem[40960];

    const int tid = threadIdx.x;
    const int wid = tid >> 6;
    const int lane = tid & 63;
    const int l15 = lane & 15;
    const int lhi = lane >> 4;
    const int win = blockIdx.x;
    const int wm  = win % nW;
    const int h   = wid;
    unsigned char* sl = smem + 16384 + h * 6144;

#define LDX(row, colb) (*reinterpret_cast<const bf16x8*>( \
        &smem[(row) * 256 + ((colb) ^ (((row) & 7) << 4))]))

    // ---------- early comb prefetch (qt=0): latency hides under QKV ----------
    const unsigned short* cwh = USE_COMB ? comb + ((size_t)(wm * NHEAD + h) << 12) : nullptr;
    uint2 cb[4];
    if (USE_COMB) {
#pragma unroll
        for (int kt = 0; kt < 4; ++kt)
            cb[kt] = *reinterpret_cast<const uint2*>(cwh + l15 * 64 + kt * 16 + lhi * 4);
    }

    // ---------- stage x -> LDS bf16, once per block ----------
    const float* xw = x + (size_t)win * (NTOK * CDIM);
#pragma unroll
    for (int i = 0; i < 4; ++i) {
        const int c = tid + i * 256;          // 0..1023
        const int row = c >> 4, col8 = c & 15;
        float4 a = {0.f, 0.f, 0.f, 0.f}, b = {0.f, 0.f, 0.f, 0.f};
        if (row < NTOK) {
            const float4* p = reinterpret_cast<const float4*>(xw + row * CDIM + col8 * 8);
            a = p[0]; b = p[1];
        }
        uint4 u;
        u.x = pk2(a.x, a.y); u.y = pk2(a.z, a.w);
        u.z = pk2(b.x, b.y); u.w = pk2(b.z, b.w);
        *reinterpret_cast<uint4*>(&smem[row * 256 + ((col8 * 16) ^ ((row & 7) << 4))]) = u;
    }
    __syncthreads();  // b0: x staged

    // ---------- Q (ch 32h..32h+31), bias in C, scale pre-folded ----------
    bf16x8 qf[4], kf[4];
#pragma unroll
    for (int cc = 0; cc < 2; ++cc) {
        const int ch0 = h * 32 + cc * 16;
        bf16x8 wf[4];
#pragma unroll
        for (int ks = 0; ks < 4; ++ks)
            wf[ks] = *reinterpret_cast<const bf16x8*>(wq + (ch0 + l15) * CDIM + ks * 32 + lhi * 8);
        const float4 b4 = *reinterpret_cast<const float4*>(qb2 + ch0 + lhi * 4);
#pragma unroll
        for (int tt = 0; tt < 4; ++tt) {
            const int row = tt * 16 + l15;
            f32x4 acc = {b4.x, b4.y, b4.z, b4.w};
#pragma unroll
            for (int ks = 0; ks < 4; ++ks)
                acc = MFMA(wf[ks], LDX(row, ks * 64 + lhi * 16), acc, 0, 0, 0);
            uint2 u; u.x = pk2(acc[0], acc[1]); u.y = pk2(acc[2], acc[3]);
            *reinterpret_cast<uint2*>(&sl[row * 80 + cc * 32 + lhi * 8]) = u;
        }
    }
#pragma unroll
    for (int t = 0; t < 4; ++t)
        qf[t] = *reinterpret_cast<const bf16x8*>(&sl[(t * 16 + l15) * 80 + lhi * 16]);

    // ---------- K (ch 128+32h..), overwrites Q region (same-wave in-order) ----------
#pragma unroll
    for (int cc = 0; cc < 2; ++cc) {
        const int ch0 = 128 + h * 32 + cc * 16;
        bf16x8 wf[4];
#pragma unroll
        for (int ks = 0; ks < 4; ++ks)
            wf[ks] = *reinterpret_cast<const bf16x8*>(wq + (ch0 + l15) * CDIM + ks * 32 + lhi * 8);
        const float4 b4 = *reinterpret_cast<const float4*>(qb2 + ch0 + lhi * 4);
#pragma unroll
        for (int tt = 0; tt < 4; ++tt) {
            const int row = tt * 16 + l15;
            f32x4 acc = {b4.x, b4.y, b4.z, b4.w};
#pragma unroll
            for (int ks = 0; ks < 4; ++ks)
                acc = MFMA(wf[ks], LDX(row, ks * 64 + lhi * 16), acc, 0, 0, 0);
            uint2 u; u.x = pk2(acc[0], acc[1]); u.y = pk2(acc[2], acc[3]);
            *reinterpret_cast<uint2*>(&sl[row * 80 + cc * 32 + lhi * 8]) = u;
        }
    }
#pragma unroll
    for (int t = 0; t < 4; ++t)
        kf[t] = *reinterpret_cast<const bf16x8*>(&sl[(t * 16 + l15) * 80 + lhi * 16]);

    // ---------- V (ch 256+32h..), normal mfma -> vt[ch][tok], overwrites Q/K region ----------
#pragma unroll
    for (int cc = 0; cc < 2; ++cc) {
        const int ch0 = 256 + h * 32 + cc * 16;
        bf16x8 wf[4];
#pragma unroll
        for (int ks = 0; ks < 4; ++ks)
            wf[ks] = *reinterpret_cast<const bf16x8*>(wq + (ch0 + l15) * CDIM + ks * 32 + lhi * 8);
        const float bs = qb2[ch0 + l15];
        const int ch = cc * 16 + l15;         // head-relative channel 0..31
#pragma unroll
        for (int tt = 0; tt < 4; ++tt) {
            const int row = tt * 16 + l15;
            f32x4 acc = {bs, bs, bs, bs};
#pragma unroll
            for (int ks = 0; ks < 4; ++ks)
                acc = MFMA(LDX(row, ks * 64 + lhi * 16), wf[ks], acc, 0, 0, 0);
            uint2 u; u.x = pk2(acc[0], acc[1]); u.y = pk2(acc[2], acc[3]);
            *reinterpret_cast<uint2*>(&sl[ch * 128 + ((tt * 32 + lhi * 8) ^ ((ch & 3) << 4))]) = u;
        }
    }
    bf16x8 vf[2][2];
#pragma unroll
    for (int dt = 0; dt < 2; ++dt)
#pragma unroll
        for (int ks = 0; ks < 2; ++ks)
            vf[dt][ks] = *reinterpret_cast<const bf16x8*>(
                &sl[(dt * 16 + l15) * 128 + ((ks * 64 + lhi * 16) ^ ((l15 & 3) << 4))]);

    __syncthreads();  // b1: all waves done with x region -> attnout may overwrite it

    // ---------- attention (private slice; attnout written per-qt, no ou regs) ----------
    unsigned char* Pb = sl + 4096;
#pragma unroll
    for (int qt = 0; qt < 4; ++qt) {
        uint2 cbn[4];
        if (USE_COMB && qt < 3) {
#pragma unroll
            for (int kt = 0; kt < 4; ++kt)
                cbn[kt] = *reinterpret_cast<const uint2*>(
                    cwh + ((qt + 1) * 16 + l15) * 64 + kt * 16 + lhi * 4);
        }
        f32x4 sv[4];
#pragma unroll
        for (int kt = 0; kt < 4; ++kt) {
            f32x4 c;
            if (USE_COMB) {
                c[0] = bflo(cb[kt].x); c[1] = bfhi(cb[kt].x);
                c[2] = bflo(cb[kt].y); c[3] = bfhi(cb[kt].y);
            } else {
                const int q = qt * 16 + l15;
#pragma unroll
                for (int r = 0; r < 4; ++r) {
                    const int key = kt * 16 + lhi * 4 + r;
                    float v;
                    if (key >= NTOK)    v = -1e30f;
                    else if (q >= NTOK) v = 0.0f;
                    else v = (rpb[rel[q * NTOK + key] * NHEAD + h] +
                              mask[(size_t)wm * (NTOK * NTOK) + q * NTOK + key]) * LOG2E;
                    c[r] = v;
                }
            }
            sv[kt] = MFMA(kf[kt], qf[qt], c, 0, 0, 0);  // S[key=16kt+4lhi+r][q=16qt+l15], log2-domain
        }
        // max tree (max3-fusable)
        float a0 = fmaxf(fmaxf(sv[0][0], sv[0][1]), fmaxf(sv[0][2], sv[0][3]));
        float a1 = fmaxf(fmaxf(sv[1][0], sv[1][1]), fmaxf(sv[1][2], sv[1][3]));
        float a2 = fmaxf(fmaxf(sv[2][0], sv[2][1]), fmaxf(sv[2][2], sv[2][3]));
        float a3 = fmaxf(fmaxf(sv[3][0], sv[3][1]), fmaxf(sv[3][2], sv[3][3]));
        float m = fmaxf(fmaxf(a0, a1), fmaxf(a2, a3));
        m = fmaxf(m, __shfl_xor(m, 16));
        m = fmaxf(m, __shfl_xor(m, 32));
#pragma unroll
        for (int kt = 0; kt < 4; ++kt) {
            sv[kt][0] = exp2f(sv[kt][0] - m);
            sv[kt][1] = exp2f(sv[kt][1] - m);
            sv[kt][2] = exp2f(sv[kt][2] - m);
            sv[kt][3] = exp2f(sv[kt][3] - m);
        }
        float s0 = (sv[0][0] + sv[0][1]) + (sv[0][2] + sv[0][3]);
        float s1 = (sv[1][0] + sv[1][1]) + (sv[1][2] + sv[1][3]);
        float s2 = (sv[2][0] + sv[2][1]) + (sv[2][2] + sv[2][3]);
        float s3 = (sv[3][0] + sv[3][1]) + (sv[3][2] + sv[3][3]);
        float sum = (s0 + s1) + (s2 + s3);
        sum += __shfl_xor(sum, 16);
        sum += __shfl_xor(sum, 32);
        const float iv = __builtin_amdgcn_rcpf(sum);

        // P write (single buffer; same-wave in-order) then fragment read
#pragma unroll
        for (int kt = 0; kt < 4; ++kt) {
            uint2 u; u.x = pk2(sv[kt][0], sv[kt][1]); u.y = pk2(sv[kt][2], sv[kt][3]);
            *reinterpret_cast<uint2*>(
                &Pb[l15 * 128 + ((kt * 32 + lhi * 8) ^ ((l15 & 3) << 4))]) = u;
        }
        bf16x8 pf0 = *reinterpret_cast<const bf16x8*>(&Pb[l15 * 128 + ((lhi * 16) ^ ((l15 & 3) << 4))]);
        bf16x8 pf1 = *reinterpret_cast<const bf16x8*>(&Pb[l15 * 128 + ((64 + lhi * 16) ^ ((l15 & 3) << 4))]);
        f32x4 o0 = {0.f, 0.f, 0.f, 0.f}, o1 = {0.f, 0.f, 0.f, 0.f};
        o0 = MFMA(vf[0][0], pf0, o0, 0, 0, 0);
        o0 = MFMA(vf[0][1], pf1, o0, 0, 0, 0);
        o1 = MFMA(vf[1][0], pf0, o1, 0, 0, 0);
        o1 = MFMA(vf[1][1], pf1, o1, 0, 0, 0);

        // attnout [64 tok][128 ch] @ smem[0,16K): write immediately (x dead since b1)
        const int row = qt * 16 + l15;
        uint2 u0, u1;
        u0.x = pk2(o0[0] * iv, o0[1] * iv);
        u0.y = pk2(o0[2] * iv, o0[3] * iv);
        u1.x = pk2(o1[0] * iv, o1[1] * iv);
        u1.y = pk2(o1[2] * iv, o1[3] * iv);
        *reinterpret_cast<uint2*>(&smem[row * 256 + ((h * 64 + lhi * 8) ^ ((row & 7) << 4))]) = u0;
        *reinterpret_cast<uint2*>(&smem[row * 256 + ((h * 64 + 32 + lhi * 8) ^ ((row & 7) << 4))]) = u1;

        if (USE_COMB && qt < 3) {
#pragma unroll
            for (int kt = 0; kt < 4; ++kt) cb[kt] = cbn[kt];
        }
    }

    // ---------- proj weight load (low-pressure region; latency hides under b2) ----------
    bf16x8 wpf[2][4];
    float4 pb4[2];
#pragma unroll
    for (int ct = 0; ct < 2; ++ct) {
        const int ocb = wid * 32 + ct * 16;
#pragma unroll
        for (int ks = 0; ks < 4; ++ks)
            wpf[ct][ks] = *reinterpret_cast<const bf16x8*>(wp + (ocb + l15) * CDIM + ks * 32 + lhi * 8);
        pb4[ct] = *reinterpret_cast<const float4*>(proj_b + ocb + lhi * 4);
    }
    __syncthreads();  // b2: attnout ready

    // ---------- proj: bias in C, float4 stores ----------
    float* ow = out + (size_t)win * (NTOK * CDIM);
#pragma unroll
    for (int tt = 0; tt < 4; ++tt) {
        const int row = tt * 16 + l15;
        bf16x8 a4[4];
#pragma unroll
        for (int ks = 0; ks < 4; ++ks) a4[ks] = LDX(row, ks * 64 + lhi * 16);
#pragma unroll
        for (int ct = 0; ct < 2; ++ct) {
            f32x4 c = {pb4[ct].x, pb4[ct].y, pb4[ct].z, pb4[ct].w};
#pragma unroll
            for (int ks = 0; ks < 4; ++ks) c = MFMA(wpf[ct][ks], a4[ks], c, 0, 0, 0);
            if (row < NTOK) {
                float4 r; r.x = c[0]; r.y = c[1]; r.z = c[2]; r.w = c[3];
                *reinterpret_cast<float4*>(ow + row * CDIM + wid * 32 + ct * 16 + lhi * 4) = r;
            }
        }
    }
#undef LDX
}

extern "C" void kernel_launch(void* const* d_in, const int* in_sizes, int n_in,
                              void* d_out, int out_size, void* d_ws, size_t ws_size,
                              hipStream_t stream) {
    const float* x      = (const float*)d_in[0];
    const float* mask   = (const float*)d_in[1];
    const float* qkv_w  = (const float*)d_in[2];
    const float* qkv_b  = (const float*)d_in[3];
    const float* proj_w = (const float*)d_in[4];
    const float* proj_b = (const float*)d_in[5];
    const float* rpb    = (const float*)d_in[6];
    const int*   rel    = (const int*)d_in[7];

    const int Bw = in_sizes[0] / (NTOK * CDIM);   // 16384
    const int nW = in_sizes[1] / (NTOK * NTOK);   // 1024

    unsigned short* wq   = (unsigned short*)d_ws;                      // 384*128 bf16
    unsigned short* wp   = wq + 384 * 128;                             // 128*128 bf16
    float*          qb2  = (float*)(wp + 128 * 128);                   // 384 f32
    unsigned short* comb = (unsigned short*)(qb2 + 384);               // nW*4*4096 bf16
    const size_t need = (size_t)(384 * 128 + 128 * 128) * 2 + 384 * 4 +
                        (size_t)nW * NHEAD * 4096 * 2;

    prep_w<<<dim3(192), dim3(256), 0, stream>>>(qkv_w, proj_w, qkv_b, wq, wp, qb2);
    if (ws_size >= need) {
        const int nComb = nW * NHEAD * 4096;
        prep_comb<<<dim3((nComb + 255) / 256), dim3(256), 0, stream>>>(mask, rpb, rel, comb, nW);
        win_attn_kernel<true><<<dim3(Bw), dim3(256), 0, stream>>>(
            x, qb2, proj_b, wq, wp, comb, mask, rpb, rel, (float*)d_out, nW);
    } else {
        win_attn_kernel<false><<<dim3(Bw), dim3(256), 0, stream>>>(
            x, qb2, proj_b, wq, wp, nullptr, mask, rpb, rel, (float*)d_out, nW);
    }
}